// Round 1
// baseline (239.345 us; speedup 1.0000x reference)
//
#include <hip/hip_runtime.h>

#define N_NODES 100000
#define N_EDGES 1600000
#define D_FEAT  64

#define RSHIFT 8
#define RPB    256                              // rows per bucket
#define NBK    ((N_NODES + RPB - 1) / RPB)      // 391 row-buckets
#define CAP    5120                             // bucket edge capacity (even; 16B-aligned base)
#define EPB    4096                             // edges per bin block
#define KBLK   ((N_EDGES + EPB - 1) / EPB)      // 391 bin blocks
#define OROW   (NBK + 1)
#define CVB    ((N_NODES * D_FEAT / 4 + 1023) / 1024)  // 1563 convert blocks
#define NPBIN  64                               // npair bins for degree-balanced packing

typedef float f32x2 __attribute__((ext_vector_type(2)));

__device__ __forceinline__ unsigned short f2bf(float f) {
  union { float f; unsigned int i; } v; v.f = f;
  unsigned int b = v.i;
  return (unsigned short)((b + 0x7FFFu + ((b >> 16) & 1u)) >> 16);  // RNE
}
__device__ __forceinline__ float ulo(int u) { return __int_as_float(u << 16); }
__device__ __forceinline__ float uhi(int u) { return __int_as_float(u & 0xFFFF0000); }
__device__ __forceinline__ f32x2 upk(int u) {  // {elem0, elem1} of a bf16 pair
  f32x2 r; r.x = ulo(u); r.y = uhi(u); return r;
}
__device__ __forceinline__ int pk(float a, float b) {
  return (int)f2bf(a) | ((int)f2bf(b) << 16);
}

// ---- fused: blocks [0,KBLK) bin edges; blocks [KBLK, KBLK+CVB) convert x ----
__global__ __launch_bounds__(1024) void convert_bin(
    const float4* __restrict__ xin, ushort4* __restrict__ xout,
    const int* __restrict__ erow, const int* __restrict__ ecol,
    const float* __restrict__ evals, int2* __restrict__ tmp,
    int* __restrict__ offs, int* __restrict__ dhist) {
  __shared__ int hist[NBK];
  __shared__ int sc[NBK];
  int t = threadIdx.x;
  int k = blockIdx.x;
  if (k == 0 && t < NPBIN) dhist[t] = 0;   // zero the npair histogram for build_csr
  if (k >= KBLK) {                       // ---- convert path ----
    int i = (k - KBLK) * 1024 + t;
    if (i < N_NODES * D_FEAT / 4) {
      float4 v = xin[i];
      ushort4 o;
      o.x = f2bf(v.x); o.y = f2bf(v.y); o.z = f2bf(v.z); o.w = f2bf(v.w);
      xout[i] = o;
    }
    return;
  }
  // ---- bin path: block-local counting sort of 4096 edges by bucket ----
  if (t < NBK) hist[t] = 0;
  __syncthreads();
  int base = k * EPB;
  int nk = N_EDGES - base; if (nk > EPB) nk = EPB;
  int key[4], vb[4], rk[4], bk[4];
#pragma unroll
  for (int j = 0; j < 4; ++j) {
    int li = j * 1024 + t;
    bk[j] = -1;
    if (li < nk) {
      int e = base + li;
      int r = erow[e];
      key[j] = ((r & (RPB - 1)) << 17) | ecol[e];
      vb[j]  = __float_as_int(evals[e]);
      bk[j]  = r >> RSHIFT;
      rk[j]  = atomicAdd(&hist[bk[j]], 1);
    }
  }
  __syncthreads();
  if (t < NBK) sc[t] = hist[t];
  __syncthreads();
  for (int off = 1; off < NBK; off <<= 1) {
    int u = (t >= off && t < NBK) ? sc[t - off] : 0;
    __syncthreads();
    if (t < NBK) sc[t] += u;
    __syncthreads();
  }
  if (t < NBK) {
    int ex = sc[t] - hist[t];
    sc[t] = ex;
    offs[k * OROW + t] = ex;
  }
  if (t == 0) offs[k * OROW + NBK] = nk;
  __syncthreads();
#pragma unroll
  for (int j = 0; j < 4; ++j) {
    if (bk[j] >= 0) {
      int pos = sc[bk[j]] + rk[j];
      tmp[k * EPB + pos] = make_int2(key[j], vb[j]);
    }
  }
}

// ---- pass 2: octet-per-run sweep. Rows padded to EVEN edge counts so every
// row starts 16B-aligned in the edge array (pad edge = {0,0} adds nothing).
// Also accumulates a global npair histogram (LDS-aggregated) for the
// degree-balanced row permutation.
__global__ __launch_bounds__(256) void build_csr(
    const int2* __restrict__ tmp, const int* __restrict__ offs,
    int2* __restrict__ edges, int* __restrict__ row_beg,
    int* __restrict__ row_end, int* __restrict__ dhist) {
  __shared__ int hist[RPB];
  __shared__ int cur[RPB];
  __shared__ int dh[NPBIN];
  int b = blockIdx.x;
  int t = threadIdx.x;
  int oct = t >> 3;        // 32 octets per block
  int ol  = t & 7;
  hist[t] = 0;
  if (t < NPBIN) dh[t] = 0;
  __syncthreads();
  for (int k = oct; k < KBLK; k += 32) {
    int o0 = offs[k * OROW + b];
    int o1 = offs[k * OROW + b + 1];
    const int2* seg = tmp + k * EPB;
    for (int i = o0 + ol; i < o1; i += 8)
      atomicAdd(&hist[seg[i].x >> 17], 1);
  }
  __syncthreads();
  int v  = hist[t];
  int v2 = (v + 1) & ~1;   // even-padded length
  cur[t] = v2;
  int gr = b * RPB + t;
  {
    int np  = v2 >> 1;                 // npair = ceil(deg/2) = loop trip count
    int bin = np > (NPBIN - 1) ? (NPBIN - 1) : np;
    if (gr < N_NODES) atomicAdd(&dh[bin], 1);
  }
  __syncthreads();
  if (t < NPBIN) { int c = dh[t]; if (c) atomicAdd(&dhist[t], c); }
  for (int off = 1; off < 256; off <<= 1) {
    int u = (t >= off) ? cur[t - off] : 0;
    __syncthreads();
    cur[t] += u;
    __syncthreads();
  }
  int excl2 = cur[t] - v2;
  int base = b * CAP;
  if (gr < N_NODES) {
    row_beg[gr] = base + excl2;
    row_end[gr] = base + excl2 + v;
  }
  if (v & 1) edges[base + excl2 + v] = make_int2(0, 0);  // zero pad slot
  __syncthreads();
  cur[t] = excl2;
  __syncthreads();
  for (int k = oct; k < KBLK; k += 32) {
    int o0 = offs[k * OROW + b];
    int o1 = offs[k * OROW + b + 1];
    const int2* seg = tmp + k * EPB;
    for (int i = o0 + ol; i < o1; i += 8) {
      int2 ed = seg[i];
      int pos = atomicAdd(&cur[ed.x >> 17], 1);
      edges[base + pos] = make_int2(ed.x & 0x1FFFF, ed.y);
    }
  }
}

// ---- exclusive scan of the 64-bin npair histogram (one wave) ----
__global__ __launch_bounds__(64) void scan64(const int* __restrict__ dhist,
                                             int* __restrict__ gbase) {
  int t = threadIdx.x;
  int v = dhist[t];
  int s = v;
  for (int off = 1; off < 64; off <<= 1) {
    int u = __shfl_up(s, off);
    if (t >= off) s += u;
  }
  gbase[t] = s - v;   // exclusive
}

// ---- build degree-balanced slot table: prows[slot] = {e0, e1, orig_row} ----
// Rows grouped by identical npair so every octet in a spmm wave runs the
// exact same trip count (zero divergence).
__global__ __launch_bounds__(256) void perm_scatter(
    const int* __restrict__ row_beg, const int* __restrict__ row_end,
    int* __restrict__ gbase, int4* __restrict__ prows) {
  __shared__ int lh[NPBIN];
  __shared__ int lbase[NPBIN];
  int t = threadIdx.x;
  int r = blockIdx.x * 256 + t;
  if (t < NPBIN) lh[t] = 0;
  __syncthreads();
  int e0 = 0, e1 = 0, bin = 0, rank = 0;
  bool valid = r < N_NODES;
  if (valid) {
    e0 = row_beg[r];
    e1 = row_end[r];
    int np = (e1 - e0 + 1) >> 1;
    bin = np > (NPBIN - 1) ? (NPBIN - 1) : np;
    rank = atomicAdd(&lh[bin], 1);
  }
  __syncthreads();
  if (t < NPBIN) { int c = lh[t]; lbase[t] = c ? atomicAdd(&gbase[t], c) : 0; }
  __syncthreads();
  if (valid) prows[lbase[bin] + rank] = make_int4(e0, e1, r, 0);
}

// ---- SpMM: ONE OCTET PER ROW (8 lanes x int4 = the full 128B feature row).
// 8 rows per wave via the degree-balanced slot table (uniform trip counts),
// zero shuffles, zero LDS. Software-pipelined: next edge pair loads issued
// before current pair's MLP so edge latency hides under gathers+FMA.
__global__ __launch_bounds__(256) void spmm_oct(
    const int4* __restrict__ prows, const int2* __restrict__ edges,
    const int4* __restrict__ xq, int4* __restrict__ h_q,
    float4* __restrict__ out, const int4* __restrict__ add1,
    const int4* __restrict__ add2, int final_mode) {
  int t = threadIdx.x;
  int lane = t & 63;
  int oct = lane >> 3;     // 0..7: row within wave
  int ol  = lane & 7;      // 0..7: which 16B of the 128B row
  int slot = blockIdx.x * 32 + (t >> 6) * 8 + oct;  // grid exact: 3125*32=100000
  int4 pr = prows[slot];
  int e0 = pr.x, e1 = pr.y;
  int row = pr.z;
  const int4* ep = (const int4*)edges + (e0 >> 1);  // e0 even
  // Round UP: odd lengths include the (real, pad) pair; pad {0,0} adds 0.
  int npair = (e1 - e0 + 1) >> 1;
  f32x2 c0 = {0.f, 0.f}, c1 = {0.f, 0.f}, c2 = {0.f, 0.f}, c3 = {0.f, 0.f};

#define PAIR(m) { \
    int4 g0 = xq[(size_t)(m).x * 8 + ol]; \
    int4 g1 = xq[(size_t)(m).z * 8 + ol]; \
    float v0 = __int_as_float((m).y), v1 = __int_as_float((m).w); \
    f32x2 vv0 = {v0, v0}, vv1 = {v1, v1}; \
    c0 += vv0 * upk(g0.x) + vv1 * upk(g1.x); \
    c1 += vv0 * upk(g0.y) + vv1 * upk(g1.y); \
    c2 += vv0 * upk(g0.z) + vv1 * upk(g1.z); \
    c3 += vv0 * upk(g0.w) + vv1 * upk(g1.w); \
  }

  int np2 = npair & ~1;
  if (np2) {
    int4 m0 = ep[0];
    int4 m1 = ep[1];
    for (int p = 2; p < np2; p += 2) {   // prefetch next pair before current MLP
      int4 n0 = ep[p];
      int4 n1 = ep[p + 1];
      PAIR(m0);
      PAIR(m1);
      m0 = n0;
      m1 = n1;
    }
    PAIR(m0);
    PAIR(m1);
  }
  if (npair & 1) {
    int4 m0 = ep[npair - 1];
    PAIR(m0);
  }
#undef PAIR

  size_t oi = (size_t)row * 8 + ol;
  if (final_mode) {
    int4 r1 = add1[oi];
    int4 r2 = add2[oi];
    float4 lo, hi;
    lo.x = c0.x + ulo(r1.x) + ulo(r2.x);
    lo.y = c0.y + uhi(r1.x) + uhi(r2.x);
    lo.z = c1.x + ulo(r1.y) + ulo(r2.y);
    lo.w = c1.y + uhi(r1.y) + uhi(r2.y);
    hi.x = c2.x + ulo(r1.z) + ulo(r2.z);
    hi.y = c2.y + uhi(r1.z) + uhi(r2.z);
    hi.z = c3.x + ulo(r1.w) + ulo(r2.w);
    hi.w = c3.y + uhi(r1.w) + uhi(r2.w);
    out[(size_t)row * 16 + ol * 2]     = lo;
    out[(size_t)row * 16 + ol * 2 + 1] = hi;
  } else {
    int4 pq;
    pq.x = pk(c0.x, c0.y);
    pq.y = pk(c1.x, c1.y);
    pq.z = pk(c2.x, c2.y);
    pq.w = pk(c3.x, c3.y);
    h_q[oi] = pq;
  }
}

extern "C" void kernel_launch(void* const* d_in, const int* in_sizes, int n_in,
                              void* d_out, int out_size, void* d_ws, size_t ws_size,
                              hipStream_t stream) {
  const float* x     = (const float*)d_in[0];
  const int*   erow  = (const int*)d_in[1];
  const int*   ecol  = (const int*)d_in[2];
  const float* evals = (const float*)d_in[3];
  float* out = (float*)d_out;

  const size_t hb_bytes   = (size_t)N_NODES * D_FEAT * 2;     // 12.8 MB (bf16)
  const size_t ecap_bytes = (size_t)NBK * CAP * sizeof(int2); // 16.0 MB
  char* ws = (char*)d_ws;
  int4*    xbf  = (int4*)   (ws);                        // 12.8 MB, live whole launch
  int4*    bufA = (int4*)   (ws + hb_bytes);             // h1 (bf16)
  int2*    tmp  = (int2*)   (ws + hb_bytes);             // aliases bufA (build only)
  int4*    bufB = (int4*)   (ws + 2 * hb_bytes);         // h2 (bf16)
  int*     offs = (int*)    (ws + 2 * hb_bytes);         // aliases bufB (build only)
  int2* edges   = (int2*)(ws + 3 * hb_bytes);
  int* row_beg  = (int*) (ws + 3 * hb_bytes + ecap_bytes);
  int* row_end  = (int*) (ws + 3 * hb_bytes + ecap_bytes + 400000);
  char* pext    = ws + 3 * hb_bytes + ecap_bytes + 800000;   // 16B-aligned
  int4* prows   = (int4*)(pext);                          // 1.6 MB slot table
  int*  dhist   = (int*) (pext + 1600000);                // 64 ints
  int*  gbase   = dhist + NPBIN;                          // 64 ints

  const int sblocks = N_NODES / 32;                        // 3125 (8 rows/wave)
  const int rblocks = (N_NODES + 255) / 256;               // 391

  // ---- fused convert + bin (1 dispatch), then CSR finalize ----
  convert_bin<<<KBLK + CVB, 1024, 0, stream>>>(
      (const float4*)x, (ushort4*)xbf, erow, ecol, evals, tmp, offs, dhist);
  build_csr<<<NBK, 256, 0, stream>>>(tmp, offs, edges, row_beg, row_end, dhist);
  // ---- degree-balanced row permutation (bin by npair) ----
  scan64<<<1, 64, 0, stream>>>(dhist, gbase);
  perm_scatter<<<rblocks, 256, 0, stream>>>(row_beg, row_end, gbase, prows);

  // L1: bufA = bf16(A xbf)      (tmp dead after build)
  spmm_oct<<<sblocks, 256, 0, stream>>>(prows, edges, xbf,
                                        bufA, nullptr, nullptr, nullptr, 0);
  // L2: bufB = bf16(A bufA)     (offs dead)
  spmm_oct<<<sblocks, 256, 0, stream>>>(prows, edges, bufA,
                                        bufB, nullptr, nullptr, nullptr, 0);
  // L3: out = A bufB + bufA + bufB   (f32 output)
  spmm_oct<<<sblocks, 256, 0, stream>>>(prows, edges, bufB,
                                        nullptr, (float4*)out, bufA, bufB, 1);
}

// Round 2
// 228.006 us; speedup vs baseline: 1.0497x; 1.0497x over previous
//
#include <hip/hip_runtime.h>

#define N_NODES 100000
#define N_EDGES 1600000
#define D_FEAT  64

#define RSHIFT 8
#define RPB    256                              // rows per bucket
#define NBK    ((N_NODES + RPB - 1) / RPB)      // 391 row-buckets
#define CAP    5120                             // bucket edge capacity (even; 16B-aligned base)
#define EPB    4096                             // edges per bin block
#define KBLK   ((N_EDGES + EPB - 1) / EPB)      // 391 bin blocks
#define OROW   (NBK + 1)
#define CVB    ((N_NODES * D_FEAT / 4 + 1023) / 1024)  // 1563 convert blocks

typedef float f32x2 __attribute__((ext_vector_type(2)));

__device__ __forceinline__ unsigned short f2bf(float f) {
  union { float f; unsigned int i; } v; v.f = f;
  unsigned int b = v.i;
  return (unsigned short)((b + 0x7FFFu + ((b >> 16) & 1u)) >> 16);  // RNE
}
__device__ __forceinline__ float ulo(int u) { return __int_as_float(u << 16); }
__device__ __forceinline__ float uhi(int u) { return __int_as_float(u & 0xFFFF0000); }
__device__ __forceinline__ f32x2 upk(int u) {  // {elem0, elem1} of a bf16 pair
  f32x2 r; r.x = ulo(u); r.y = uhi(u); return r;
}
__device__ __forceinline__ int pk(float a, float b) {
  return (int)f2bf(a) | ((int)f2bf(b) << 16);
}

// ---- fused: blocks [0,KBLK) bin edges; blocks [KBLK, KBLK+CVB) convert x ----
__global__ __launch_bounds__(1024) void convert_bin(
    const float4* __restrict__ xin, ushort4* __restrict__ xout,
    const int* __restrict__ erow, const int* __restrict__ ecol,
    const float* __restrict__ evals, int2* __restrict__ tmp,
    int* __restrict__ offs) {
  __shared__ int hist[NBK];
  __shared__ int sc[NBK];
  int t = threadIdx.x;
  int k = blockIdx.x;
  if (k >= KBLK) {                       // ---- convert path ----
    int i = (k - KBLK) * 1024 + t;
    if (i < N_NODES * D_FEAT / 4) {
      float4 v = xin[i];
      ushort4 o;
      o.x = f2bf(v.x); o.y = f2bf(v.y); o.z = f2bf(v.z); o.w = f2bf(v.w);
      xout[i] = o;
    }
    return;
  }
  // ---- bin path: block-local counting sort of 4096 edges by bucket ----
  if (t < NBK) hist[t] = 0;
  __syncthreads();
  int base = k * EPB;
  int nk = N_EDGES - base; if (nk > EPB) nk = EPB;
  int key[4], vb[4], rk[4], bk[4];
#pragma unroll
  for (int j = 0; j < 4; ++j) {
    int li = j * 1024 + t;
    bk[j] = -1;
    if (li < nk) {
      int e = base + li;
      int r = erow[e];
      key[j] = ((r & (RPB - 1)) << 17) | ecol[e];
      vb[j]  = __float_as_int(evals[e]);
      bk[j]  = r >> RSHIFT;
      rk[j]  = atomicAdd(&hist[bk[j]], 1);
    }
  }
  __syncthreads();
  if (t < NBK) sc[t] = hist[t];
  __syncthreads();
  for (int off = 1; off < NBK; off <<= 1) {
    int u = (t >= off && t < NBK) ? sc[t - off] : 0;
    __syncthreads();
    if (t < NBK) sc[t] += u;
    __syncthreads();
  }
  if (t < NBK) {
    int ex = sc[t] - hist[t];
    sc[t] = ex;
    offs[k * OROW + t] = ex;
  }
  if (t == 0) offs[k * OROW + NBK] = nk;
  __syncthreads();
#pragma unroll
  for (int j = 0; j < 4; ++j) {
    if (bk[j] >= 0) {
      int pos = sc[bk[j]] + rk[j];
      tmp[k * EPB + pos] = make_int2(key[j], vb[j]);
    }
  }
}

// ---- pass 2: octet-per-run sweep, 512 threads (64 octets halve the serial
// k-sweep depth). Rows padded to EVEN edge counts so every row starts
// 16B-aligned in the edge array (pad edge = {0,0} adds nothing).
__global__ __launch_bounds__(512) void build_csr(
    const int2* __restrict__ tmp, const int* __restrict__ offs,
    int2* __restrict__ edges, int* __restrict__ row_beg,
    int* __restrict__ row_end) {
  __shared__ int hist[RPB];
  __shared__ int cur[RPB];
  int b = blockIdx.x;
  int t = threadIdx.x;
  int oct = t >> 3;        // 64 octets per block
  int ol  = t & 7;
  if (t < RPB) hist[t] = 0;
  __syncthreads();
  for (int k = oct; k < KBLK; k += 64) {
    int o0 = offs[k * OROW + b];
    int o1 = offs[k * OROW + b + 1];
    const int2* seg = tmp + k * EPB;
    for (int i = o0 + ol; i < o1; i += 8)
      atomicAdd(&hist[seg[i].x >> 17], 1);
  }
  __syncthreads();
  int v = 0, v2 = 0;
  if (t < RPB) {
    v  = hist[t];
    v2 = (v + 1) & ~1;     // even-padded length
    cur[t] = v2;
  }
  __syncthreads();
  for (int off = 1; off < RPB; off <<= 1) {
    int u = (t >= off && t < RPB) ? cur[t - off] : 0;
    __syncthreads();
    if (t < RPB) cur[t] += u;
    __syncthreads();
  }
  int excl2 = 0;
  int base = b * CAP;
  if (t < RPB) {
    excl2 = cur[t] - v2;
    int gr = b * RPB + t;
    if (gr < N_NODES) {
      row_beg[gr] = base + excl2;
      row_end[gr] = base + excl2 + v;
    }
    if (v & 1) edges[base + excl2 + v] = make_int2(0, 0);  // zero pad slot
  }
  __syncthreads();
  if (t < RPB) cur[t] = excl2;
  __syncthreads();
  for (int k = oct; k < KBLK; k += 64) {
    int o0 = offs[k * OROW + b];
    int o1 = offs[k * OROW + b + 1];
    const int2* seg = tmp + k * EPB;
    for (int i = o0 + ol; i < o1; i += 8) {
      int2 ed = seg[i];
      int pos = atomicAdd(&cur[ed.x >> 17], 1);
      edges[base + pos] = make_int2(ed.x & 0x1FFFF, ed.y);
    }
  }
}

// ---- SpMM: ONE OCTET PER ROW (8 lanes x int4 = the full 128B feature row).
// 8 consecutive rows per wave, zero shuffles, zero LDS. Double-buffered
// software pipeline: gathers for edge-block B are issued a full iteration
// before their FMAs, so ~8 gathers + 2 edge loads stay in flight per wave
// and the FMA phase never waits on same-iteration loads.
__global__ __launch_bounds__(256) void spmm_oct(
    const int* __restrict__ row_beg, const int* __restrict__ row_end,
    const int2* __restrict__ edges, const int4* __restrict__ xq,
    int4* __restrict__ h_q, float4* __restrict__ out,
    const int4* __restrict__ add1, const int4* __restrict__ add2,
    int final_mode) {
  int t = threadIdx.x;
  int lane = t & 63;
  int oct = lane >> 3;     // 0..7: row within wave
  int ol  = lane & 7;      // 0..7: which 16B of the 128B row
  int row = blockIdx.x * 32 + (t >> 6) * 8 + oct;   // grid exact: 3125*32=100000
  int e0 = row_beg[row];
  int e1 = row_end[row];
  const int4* ep = (const int4*)edges + (e0 >> 1);  // e0 even
  // Round UP: odd lengths include the (real, pad) pair; pad {0,0} adds 0.
  int npair = (e1 - e0 + 1) >> 1;
  f32x2 c0 = {0.f, 0.f}, c1 = {0.f, 0.f}, c2 = {0.f, 0.f}, c3 = {0.f, 0.f};

#define GATH(g0, g1, m) \
    g0 = xq[(size_t)(m).x * 8 + ol]; \
    g1 = xq[(size_t)(m).z * 8 + ol];
#define FMA_P(g0, g1, m) { \
    float v0 = __int_as_float((m).y), v1 = __int_as_float((m).w); \
    f32x2 vv0 = {v0, v0}, vv1 = {v1, v1}; \
    c0 += vv0 * upk((g0).x) + vv1 * upk((g1).x); \
    c1 += vv0 * upk((g0).y) + vv1 * upk((g1).y); \
    c2 += vv0 * upk((g0).z) + vv1 * upk((g1).z); \
    c3 += vv0 * upk((g0).w) + vv1 * upk((g1).w); \
  }

  if (npair >= 2) {
    int4 mA0 = ep[0], mA1 = ep[1];
    int4 a0, a1, a2, a3;
    GATH(a0, a1, mA0);
    GATH(a2, a3, mA1);
    int q = 2;
    while (q + 4 <= npair) {             // 2 blocks/iter: explicit A/B rotation
      int4 mB0 = ep[q], mB1 = ep[q + 1];
      int4 b0, b1, b2, b3;
      GATH(b0, b1, mB0);
      GATH(b2, b3, mB1);
      FMA_P(a0, a1, mA0);                // consume A (issued last iteration)
      FMA_P(a2, a3, mA1);
      mA0 = ep[q + 2]; mA1 = ep[q + 3];
      GATH(a0, a1, mA0);
      GATH(a2, a3, mA1);
      FMA_P(b0, b1, mB0);                // consume B (issued this iteration)
      FMA_P(b2, b3, mB1);
      q += 4;
    }
    if (q + 2 <= npair) {                // one full block left
      int4 mB0 = ep[q], mB1 = ep[q + 1];
      int4 b0, b1, b2, b3;
      GATH(b0, b1, mB0);
      GATH(b2, b3, mB1);
      FMA_P(a0, a1, mA0);
      FMA_P(a2, a3, mA1);
      FMA_P(b0, b1, mB0);
      FMA_P(b2, b3, mB1);
      q += 2;
    } else {
      FMA_P(a0, a1, mA0);
      FMA_P(a2, a3, mA1);
    }
    if (q < npair) {                     // trailing single pair (odd npair)
      int4 m = ep[q];
      int4 g0, g1;
      GATH(g0, g1, m);
      FMA_P(g0, g1, m);
    }
  } else if (npair == 1) {
    int4 m = ep[0];
    int4 g0, g1;
    GATH(g0, g1, m);
    FMA_P(g0, g1, m);
  }
#undef GATH
#undef FMA_P

  size_t oi = (size_t)row * 8 + ol;
  if (final_mode) {
    int4 r1 = add1[oi];
    int4 r2 = add2[oi];
    float4 lo, hi;
    lo.x = c0.x + ulo(r1.x) + ulo(r2.x);
    lo.y = c0.y + uhi(r1.x) + uhi(r2.x);
    lo.z = c1.x + ulo(r1.y) + ulo(r2.y);
    lo.w = c1.y + uhi(r1.y) + uhi(r2.y);
    hi.x = c2.x + ulo(r1.z) + ulo(r2.z);
    hi.y = c2.y + uhi(r1.z) + uhi(r2.z);
    hi.z = c3.x + ulo(r1.w) + ulo(r2.w);
    hi.w = c3.y + uhi(r1.w) + uhi(r2.w);
    out[(size_t)row * 16 + ol * 2]     = lo;
    out[(size_t)row * 16 + ol * 2 + 1] = hi;
  } else {
    int4 pq;
    pq.x = pk(c0.x, c0.y);
    pq.y = pk(c1.x, c1.y);
    pq.z = pk(c2.x, c2.y);
    pq.w = pk(c3.x, c3.y);
    h_q[oi] = pq;
  }
}

extern "C" void kernel_launch(void* const* d_in, const int* in_sizes, int n_in,
                              void* d_out, int out_size, void* d_ws, size_t ws_size,
                              hipStream_t stream) {
  const float* x     = (const float*)d_in[0];
  const int*   erow  = (const int*)d_in[1];
  const int*   ecol  = (const int*)d_in[2];
  const float* evals = (const float*)d_in[3];
  float* out = (float*)d_out;

  const size_t hb_bytes   = (size_t)N_NODES * D_FEAT * 2;     // 12.8 MB (bf16)
  const size_t ecap_bytes = (size_t)NBK * CAP * sizeof(int2); // 16.0 MB
  char* ws = (char*)d_ws;
  int4*    xbf  = (int4*)   (ws);                        // 12.8 MB, live whole launch
  int4*    bufA = (int4*)   (ws + hb_bytes);             // h1 (bf16)
  int2*    tmp  = (int2*)   (ws + hb_bytes);             // aliases bufA (build only)
  int4*    bufB = (int4*)   (ws + 2 * hb_bytes);         // h2 (bf16)
  int*     offs = (int*)    (ws + 2 * hb_bytes);         // aliases bufB (build only)
  int2* edges   = (int2*)(ws + 3 * hb_bytes);
  int* row_beg  = (int*) (ws + 3 * hb_bytes + ecap_bytes);
  int* row_end  = (int*) (ws + 3 * hb_bytes + ecap_bytes + 400000);

  const int sblocks = N_NODES / 32;                        // 3125 (8 rows/wave)

  // ---- fused convert + bin (1 dispatch), then CSR finalize ----
  convert_bin<<<KBLK + CVB, 1024, 0, stream>>>(
      (const float4*)x, (ushort4*)xbf, erow, ecol, evals, tmp, offs);
  build_csr<<<NBK, 512, 0, stream>>>(tmp, offs, edges, row_beg, row_end);

  // L1: bufA = bf16(A xbf)      (tmp dead after build)
  spmm_oct<<<sblocks, 256, 0, stream>>>(row_beg, row_end, edges, xbf,
                                        bufA, nullptr, nullptr, nullptr, 0);
  // L2: bufB = bf16(A bufA)     (offs dead)
  spmm_oct<<<sblocks, 256, 0, stream>>>(row_beg, row_end, edges, bufA,
                                        bufB, nullptr, nullptr, nullptr, 0);
  // L3: out = A bufB + bufA + bufB   (f32 output)
  spmm_oct<<<sblocks, 256, 0, stream>>>(row_beg, row_end, edges, bufB,
                                        nullptr, (float4*)out, bufA, bufB, 1);
}